// Round 3
// baseline (105.013 us; speedup 1.0000x reference)
//
#include <hip/hip_runtime.h>

#define NTHR 512
#define TB 32

typedef __attribute__((ext_vector_type(8))) short bf16x8;
typedef __attribute__((ext_vector_type(4))) float f32x4;
typedef float4 f4;
typedef unsigned short u16;

__device__ __forceinline__ u16 f2b(float x) {
  union { float f; unsigned u; } v; v.f = x;
  unsigned r = (v.u + 0x7fffu + ((v.u >> 16) & 1u)) >> 16;
  return (u16)r;
}
__device__ __forceinline__ float b2f(u16 u) {
  union { unsigned u; float f; } v; v.u = ((unsigned)u) << 16;
  return v.f;
}
__device__ __forceinline__ unsigned pack2(float a, float b) {
  return (unsigned)f2b(a) | ((unsigned)f2b(b) << 16);
}

// ---------------- prep: k-major bf16 weight copies in ws ----------------
// BT [a][n=144][kk=320]  : T[a,p,q,r,s], n=p*16+s, kk=q*17+r (pad>=289 -> 0)
// UcT[c][n=64][k=256]    : U[c,a,k,r],   n=a*16+r
// UOT[a][h=256][kk=32]   : UO[a,s,h] transposed, kk=s (pad>=16 -> 0)
extern "C" __global__ void hosvd_prep(const float* __restrict__ U,
                                      const float* __restrict__ T,
                                      const float* __restrict__ UO,
                                      unsigned* __restrict__ ws32) {
  int id = blockIdx.x * 256 + threadIdx.x;
  if (id < 92160) {                       // BT: 4*144*160 u32
    int a = id / 23040, rem = id % 23040;
    int n = rem / 160, sl = rem % 160;
    int p = n >> 4, s = n & 15;
    int kk0 = sl * 2;
    float v[2];
    #pragma unroll
    for (int j = 0; j < 2; ++j) {
      int kk = kk0 + j;
      float x = 0.f;
      if (kk < 289) {
        int qq = (unsigned)kk / 17u, rr = kk - qq * 17;
        x = T[(((a * 9 + p) * 17 + qq) * 17 + rr) * 16 + s];
      }
      v[j] = x;
    }
    ws32[id] = pack2(v[0], v[1]);
  } else if (id < 108544) {               // UcT: 2*64*128 u32
    int rel = id - 92160;
    int c = rel / 8192, n = (rel / 128) & 63, kp = rel & 127;
    int a = n >> 4, r = n & 15, k0 = kp * 2;
    float v0 = U[((c * 4 + a) * 256 + k0 + 0) * 16 + r];
    float v1 = U[((c * 4 + a) * 256 + k0 + 1) * 16 + r];
    ws32[id] = pack2(v0, v1);
  } else if (id < 124928) {               // UOT: 4*256*16 u32
    int rel = id - 108544;
    int a = rel / 4096, h = (rel / 16) & 255, kp = rel & 15;
    int k0 = kp * 2;
    float v0 = (k0 + 0 < 16) ? UO[(a * 16 + k0 + 0) * 256 + h] : 0.f;
    float v1 = (k0 + 1 < 16) ? UO[(a * 16 + k0 + 1) * 256 + h] : 0.f;
    ws32[id] = pack2(v0, v1);
  }
}

// ---------------- main fused kernel ----------------
// LDS (62.5 KB -> 2 blocks/CU):
//   s_u  [32][640] u16 (40960 B): nh bf16 swz | O bf16 swz | s_red f32 4KB alias
//   s_ch [32][152] u16: h[row][c*76 + a*19 + idx], idx16=1.0, idx17=0 sentinels
//   s_tp [32][36]  f32
//   s_g  [32][140] u16 (stride 140 for bank spread; slots 16..31 per a zeroed)
extern "C" __global__ __launch_bounds__(NTHR, 4)
void hosvd_main(const float* __restrict__ nh, const float* __restrict__ te,
                const float* __restrict__ bw, const float* __restrict__ Ut,
                const float* __restrict__ bt, const float* __restrict__ bO,
                const u16* __restrict__ BT, const u16* __restrict__ UcT,
                const u16* __restrict__ UOT, float* __restrict__ out) {
  __shared__ __align__(16) u16   s_u[TB * 640];
  __shared__ __align__(16) u16   s_ch[TB * 152];
  __shared__ __align__(16) float s_tp[TB * 36];
  __shared__ __align__(16) u16   s_g[TB * 140];

  const int t = threadIdx.x;
  const int ib0 = blockIdx.x * TB;
  const int w = t >> 6, l = t & 63;
  const int rl = l & 15, q = l >> 4;
  const int m = w & 1, par = (w >> 1) & 1, w3 = w >> 2;
  const int row7 = rl & 7;

  //---- sentinel init: h[16]=1.0, h[17]=0 for every (row,c,a) ----
  {
    const int rowi = t >> 4, cc = (t >> 3) & 1, a2 = t & 7;
    const int aa = a2 >> 1, slot = a2 & 1;
    s_ch[rowi * 152 + cc * 76 + aa * 19 + 16 + slot] = slot ? 0 : (u16)0x3F80;
  }

  //---- Phase B: tp = te @ Ut + bt -> s_tp (f32), vectorized global reads ----
  {
    const int i = t >> 4, aB_ = (t >> 2) & 3, j2 = t & 3;
    const int off = aB_ * 8 + j2 * 2;
    f4 ter[8];
    #pragma unroll
    for (int k4 = 0; k4 < 8; ++k4)
      ter[k4] = *(const f4*)&te[(size_t)(ib0 + i) * 32 + k4 * 4];
    float acc0 = bt[off], acc1 = bt[off + 1];
    #pragma unroll
    for (int k4 = 0; k4 < 8; ++k4) {
      float tv;
      float2 u;
      tv = ter[k4].x; u = *(const float2*)&Ut[(k4 * 4 + 0) * 32 + off];
      acc0 = fmaf(tv, u.x, acc0); acc1 = fmaf(tv, u.y, acc1);
      tv = ter[k4].y; u = *(const float2*)&Ut[(k4 * 4 + 1) * 32 + off];
      acc0 = fmaf(tv, u.x, acc0); acc1 = fmaf(tv, u.y, acc1);
      tv = ter[k4].z; u = *(const float2*)&Ut[(k4 * 4 + 2) * 32 + off];
      acc0 = fmaf(tv, u.x, acc0); acc1 = fmaf(tv, u.y, acc1);
      tv = ter[k4].w; u = *(const float2*)&Ut[(k4 * 4 + 3) * 32 + off];
      acc0 = fmaf(tv, u.x, acc0); acc1 = fmaf(tv, u.y, acc1);
    }
    s_tp[i * 36 + off]     = acc0;
    s_tp[i * 36 + off + 1] = acc1;
  }

  //---- Phase C stage: nh -> s_u bf16, XOR-swizzled ----
  for (int lp = t; lp < 4096; lp += NTHR) {
    int rowi = lp >> 7, cc = (lp >> 6) & 1, ck = lp & 63;
    f4 v = *(const f4*)&nh[((size_t)(ib0 + rowi) * 2 + cc) * 256 + ck * 4];
    int k0 = ck * 4;
    int idx = rowi * 640 + (((cc * 40 + (k0 >> 3)) ^ (rowi & 7)) << 3) + (k0 & 7);
    *(uint2*)&s_u[idx] = make_uint2(pack2(v.x, v.y), pack2(v.z, v.w));
  }
  __syncthreads();

  //---- Phase C GEMM: ch = nh @ U + bw -> s_ch (wave: m, par, c=w3) ----
  {
    const int c = w3;
    f32x4 acc0 = {0.f, 0.f, 0.f, 0.f}, acc1 = {0.f, 0.f, 0.f, 0.f};
    const int a0 = par * 2 + 0, a1 = par * 2 + 1;
    const int n0 = a0 * 16 + rl, n1 = a1 * 16 + rl;
    #pragma unroll
    for (int kt = 0; kt < 8; ++kt) {
      int ak = kt * 32 + 8 * q;
      int aidx = (m * 16 + rl) * 640 + (((c * 40 + (ak >> 3)) ^ row7) << 3);
      bf16x8 A  = *(const bf16x8*)&s_u[aidx];
      bf16x8 B0 = *(const bf16x8*)&UcT[(c * 64 + n0) * 256 + ak];
      bf16x8 B1 = *(const bf16x8*)&UcT[(c * 64 + n1) * 256 + ak];
      acc0 = __builtin_amdgcn_mfma_f32_16x16x32_bf16(A, B0, acc0, 0, 0, 0);
      acc1 = __builtin_amdgcn_mfma_f32_16x16x32_bf16(A, B1, acc1, 0, 0, 0);
    }
    float bias0 = bw[c * 64 + n0], bias1 = bw[c * 64 + n1];
    #pragma unroll
    for (int reg = 0; reg < 4; ++reg) {
      int rowi = m * 16 + 4 * q + reg;
      s_ch[rowi * 152 + c * 76 + a0 * 19 + rl] = f2b(acc0[reg] + bias0);
      s_ch[rowi * 152 + c * 76 + a1 * 19 + rl] = f2b(acc1[reg] + bias1);
    }
  }

  //---- Core: per a-pair: O-build, p-split GEMM (p=4 shared, 0.5x), reduce ----
  float* s_red = (float*)s_u;   // 4 KB alias, guarded by barriers

  for (int aB = 0; aB < 4; aB += 2) {
    __syncthreads();   // s_ch ready / prior s_u readers done

    {  // O-build: thread -> (row, aL, 40-k chunk), running (q,r)
      const int rowi = t >> 4, aL = (t >> 3) & 1, chunk = t & 7;
      const int a = aB + aL;
      const int k0 = chunk * 40;
      int qq = (unsigned)k0 / 17u;
      int rr = k0 - qq * 17;
      const u16* h1p = &s_ch[rowi * 152 + a * 19];
      const u16* h2p = &s_ch[rowi * 152 + 76 + a * 19];
      unsigned w0 = 0, w1 = 0;
      #pragma unroll
      for (int kk = 0; kk < 40; ++kk) {
        int k = k0 + kk;
        float v = (k < 289) ? b2f(h1p[qq]) * b2f(h2p[rr]) : 0.f;
        unsigned hb = (unsigned)f2b(v);
        if ((kk & 3) == 0) w0 = hb;
        else if ((kk & 3) == 1) w0 |= hb << 16;
        else if ((kk & 3) == 2) w1 = hb;
        else {
          w1 |= hb << 16;
          int kb = k - 3;
          int idx = rowi * 640 + (((aL * 40 + (kb >> 3)) ^ (rowi & 7)) << 3) + (kb & 7);
          *(uint2*)&s_u[idx] = make_uint2(w0, w1);
        }
        if (++rr == 17) { rr = 0; ++qq; }
      }
    }
    __syncthreads();

    // GEMM vs BT: wave (m, par=a-of-pair, ph=w3 half of p's)
    const int a = aB + par;
    const int ph = w3;
    f32x4 acc[5];
    #pragma unroll
    for (int pp = 0; pp < 5; ++pp) acc[pp] = (f32x4){0.f, 0.f, 0.f, 0.f};
    #pragma unroll
    for (int kt = 0; kt < 10; ++kt) {
      int ak = kt * 32 + 8 * q;
      int aidx = (m * 16 + rl) * 640 + (((par * 40 + (ak >> 3)) ^ row7) << 3);
      bf16x8 A = *(const bf16x8*)&s_u[aidx];
      #pragma unroll
      for (int pp = 0; pp < 5; ++pp) {
        int p = ph * 4 + pp;
        bf16x8 B = *(const bf16x8*)&BT[(a * 144 + p * 16 + rl) * 320 + ak];
        acc[pp] = __builtin_amdgcn_mfma_f32_16x16x32_bf16(A, B, acc[pp], 0, 0, 0);
      }
    }

    // partial epilogue in registers (h0-weighted), p=4 shared -> 0.5x each
    float gp[4];
    #pragma unroll
    for (int reg = 0; reg < 4; ++reg) {
      int rowi = m * 16 + 4 * q + reg;
      float g = 0.f;
      #pragma unroll
      for (int pp = 0; pp < 5; ++pp) {
        int p = ph * 4 + pp;
        float c = (p == 8) ? 1.f : s_tp[rowi * 36 + a * 8 + p];
        if (p == 4) c *= 0.5f;
        g = fmaf(c, acc[pp][reg], g);
      }
      gp[reg] = g;
    }
    __syncthreads();   // all s_u GEMM reads done before s_red write

    if (ph == 1) {
      #pragma unroll
      for (int reg = 0; reg < 4; ++reg)
        s_red[(m * 2 + par) * 256 + (4 * q + reg) * 16 + rl] = gp[reg];
    }
    __syncthreads();

    if (ph == 0) {
      #pragma unroll
      for (int reg = 0; reg < 4; ++reg) {
        int rowi = m * 16 + 4 * q + reg;
        float g = gp[reg] + s_red[(m * 2 + par) * 256 + (4 * q + reg) * 16 + rl];
        s_g[rowi * 140 + a * 32 + rl]      = f2b(g);
        s_g[rowi * 140 + a * 32 + 16 + rl] = 0;   // zero K-pad for phase E
      }
    }
  }
  __syncthreads();

  //---- Phase E: out = g @ U_output + b_output (wave: m, ht0 = par*2+w3) ----
  {
    const int ht0 = par * 2 + w3;
    #pragma unroll
    for (int a = 0; a < 4; ++a) {
      bf16x8 A = *(const bf16x8*)&s_g[(m * 16 + rl) * 140 + a * 32 + 8 * q];
      #pragma unroll
      for (int j = 0; j < 4; ++j) {
        int h = (ht0 + 4 * j) * 16 + rl;
        bf16x8 B = *(const bf16x8*)&UOT[(a * 256 + h) * 32 + 8 * q];
        float bias = bO[a * 256 + h];
        f32x4 accE = {bias, bias, bias, bias};
        accE = __builtin_amdgcn_mfma_f32_16x16x32_bf16(A, B, accE, 0, 0, 0);
        #pragma unroll
        for (int reg = 0; reg < 4; ++reg)
          out[(size_t)(ib0 + m * 16 + 4 * q + reg) * 1024 + a * 256 + h] = accE[reg];
      }
    }
  }
}

extern "C" void kernel_launch(void* const* d_in, const int* in_sizes, int n_in,
                              void* d_out, int out_size, void* d_ws, size_t ws_size,
                              hipStream_t stream) {
  const float* nh = (const float*)d_in[0];
  const float* te = (const float*)d_in[1];
  const float* U  = (const float*)d_in[2];
  const float* bw = (const float*)d_in[3];
  const float* Ut = (const float*)d_in[4];
  const float* bt = (const float*)d_in[5];
  const float* T  = (const float*)d_in[6];
  const float* UO = (const float*)d_in[7];
  const float* bO = (const float*)d_in[8];
  float* out = (float*)d_out;

  unsigned* ws32 = (unsigned*)d_ws;
  hipLaunchKernelGGL(hosvd_prep, dim3(488), dim3(256), 0, stream, U, T, UO, ws32);

  const u16* BT  = (const u16*)d_ws;          // 184320 elems
  const u16* UcT = BT + 184320;               // 32768 elems
  const u16* UOT = UcT + 32768;               // 32768 elems

  const int bs = in_sizes[0] / 512;           // (BS,2,256)
  hipLaunchKernelGGL(hosvd_main, dim3(bs / TB), dim3(NTHR), 0, stream,
                     nh, te, bw, Ut, bt, bO, BT, UcT, UOT, out);
}

// Round 4
// 57.759 us; speedup vs baseline: 1.8181x; 1.8181x over previous
//
#include <hip/hip_runtime.h>

#define NTHR 512
#define TB 32

typedef __attribute__((ext_vector_type(8))) short bf16x8;
typedef __attribute__((ext_vector_type(4))) float f32x4;
typedef float4 f4;
typedef unsigned short u16;

__device__ __forceinline__ u16 f2b(float x) {
  union { float f; unsigned u; } v; v.f = x;
  unsigned r = (v.u + 0x7fffu + ((v.u >> 16) & 1u)) >> 16;
  return (u16)r;
}
__device__ __forceinline__ float b2f(u16 u) {
  union { unsigned u; float f; } v; v.u = ((unsigned)u) << 16;
  return v.f;
}
__device__ __forceinline__ unsigned pack2(float a, float b) {
  return (unsigned)f2b(a) | ((unsigned)f2b(b) << 16);
}
__device__ __forceinline__ unsigned cvtpk(float lo, float hi) {
  unsigned r;
  asm("v_cvt_pk_bf16_f32 %0, %1, %2" : "=v"(r) : "v"(lo), "v"(hi));
  return r;
}
__device__ __forceinline__ float blo(unsigned u) {
  union { unsigned u; float f; } v; v.u = u << 16; return v.f;
}
__device__ __forceinline__ float bhi(unsigned u) {
  union { unsigned u; float f; } v; v.u = u & 0xffff0000u; return v.f;
}

// ---------------- prep: MFMA-fragment-ordered bf16 weights in ws ----------------
// BTf : frag_id = (a*9+p)*10+kt, lane l, 8 k's. k' = kt*32+(l>>4)*8+j, col s = l&15.
//       k' = q*18+r mapping; k'>=306 or r==17 -> 0.
// UcTf: frag_id = (c*4+a)*8+kt;  k = kt*32+(l>>4)*8+j, col r = l&15.
// UOTf: frag_id = a*16+ht;       k = (l>>4)*8+j (k>=16 -> 0), col h = ht*16+(l&15).
extern "C" __global__ void hosvd_prep(const float* __restrict__ U,
                                      const float* __restrict__ T,
                                      const float* __restrict__ UO,
                                      unsigned* __restrict__ ws32) {
  int id = blockIdx.x * 256 + threadIdx.x;
  if (id < 92160) {                       // BTf: 23040 frags * 4 u32
    int j2 = id & 3, frag = id >> 2;
    int l = frag & 63, f2 = frag >> 6;
    int kt = f2 % 10, ap = f2 / 10;
    int p = ap % 9, a = ap / 9;
    int s = l & 15;
    float v[2];
    #pragma unroll
    for (int j = 0; j < 2; ++j) {
      int kp = kt * 32 + (l >> 4) * 8 + j2 * 2 + j;
      float x = 0.f;
      if (kp < 306) {
        int q = (unsigned)kp / 18u, r = kp - q * 18;
        if (r < 17) x = T[(((a * 9 + p) * 17 + q) * 17 + r) * 16 + s];
      }
      v[j] = x;
    }
    ws32[id] = pack2(v[0], v[1]);
  } else if (id < 108544) {               // UcTf: 4096 frags * 4 u32
    int rel = id - 92160;
    int j2 = rel & 3, frag = rel >> 2;
    int l = frag & 63, f2 = frag >> 6;
    int kt = f2 & 7, g = f2 >> 3;
    int a = g & 3, c = g >> 2;
    int rr = l & 15;
    int k = kt * 32 + (l >> 4) * 8 + j2 * 2;
    float v0 = U[((c * 4 + a) * 256 + k + 0) * 16 + rr];
    float v1 = U[((c * 4 + a) * 256 + k + 1) * 16 + rr];
    ws32[id] = pack2(v0, v1);
  } else if (id < 124928) {               // UOTf: 4096 frags * 4 u32
    int rel = id - 108544;
    int j2 = rel & 3, frag = rel >> 2;
    int l = frag & 63, f2 = frag >> 6;
    int ht = f2 & 15, a = f2 >> 4;
    int h = ht * 16 + (l & 15);
    int k = (l >> 4) * 8 + j2 * 2;
    float v0 = (k + 0 < 16) ? UO[(a * 16 + k + 0) * 256 + h] : 0.f;
    float v1 = (k + 1 < 16) ? UO[(a * 16 + k + 1) * 256 + h] : 0.f;
    ws32[id] = pack2(v0, v1);
  }
}

// ---------------- main fused kernel ----------------
// LDS (65280 B -> 2 blocks/CU):
//  s_u   [16640] u16: nh [32][520] (2c*256+pad) | O [32][328] (k'=q*18+r, 306..327 zero)
//  s_ch  [32][164] u16: h[row][c*80 + a*20 + idx]; idx16=1.0, idx17=0 sentinels
//  s_tpt [36][32] f32: tp transposed [a*9+p][row]; p=8 row = 1.0 sentinel
//  s_g   [32][136] u16: [row][a*32 + s]; slots 16..31 zero (K-pad for phase E)
//  s_red [2048] f32: te stage [32][33] (early) | k-split reduce 3*2*16*17 (late)
extern "C" __global__ __launch_bounds__(NTHR, 4)
void hosvd_main(const float* __restrict__ nh, const float* __restrict__ te,
                const float* __restrict__ bw, const float* __restrict__ Ut,
                const float* __restrict__ bt, const float* __restrict__ bO,
                const u16* __restrict__ BTf, const u16* __restrict__ UcTf,
                const u16* __restrict__ UOTf, float* __restrict__ out) {
  __shared__ __align__(16) u16   s_u[16640];
  __shared__ __align__(16) u16   s_ch[TB * 164];
  __shared__ __align__(16) float s_tpt[36 * 32];
  __shared__ __align__(16) u16   s_g[TB * 136];
  __shared__ __align__(16) float s_red[2048];

  const int t = threadIdx.x;
  const int ib0 = blockIdx.x * TB;
  const int w = t >> 6, l = t & 63;
  const int rl = l & 15, q = l >> 4;
  const int m = w & 1;

  //---- sentinels ----
  {  // s_ch: h[16]=1.0, h[17]=0 for every (row, c, a)  (exactly 512 slots)
    const int row = t >> 4, cc = (t >> 3) & 1, aa = (t >> 1) & 3, sl = t & 1;
    s_ch[row * 164 + cc * 80 + aa * 20 + 16 + sl] = sl ? (u16)0 : (u16)0x3F80;
  }
  if (t < 128) {  // s_tpt p=8 row = 1.0
    const int aa = t >> 5, row = t & 31;
    s_tpt[(aa * 9 + 8) * 32 + row] = 1.0f;
  }

  //---- stage te -> s_red[32][33], nh -> s_u bf16 [32][520] ----
  if (t < 256) {
    const int row = t >> 3, k4 = t & 7;
    f4 v = *(const f4*)&te[(size_t)(ib0 + row) * 32 + k4 * 4];
    float* d = &s_red[row * 33 + k4 * 4];
    d[0] = v.x; d[1] = v.y; d[2] = v.z; d[3] = v.w;
  }
  for (int lp = t; lp < 4096; lp += NTHR) {
    const int row = lp >> 7, rem = lp & 127;
    const int c = rem >> 6, k0 = (rem & 63) * 4;
    f4 v = *(const f4*)&nh[((size_t)(ib0 + row) * 2 + c) * 256 + k0];
    *(uint2*)&s_u[row * 520 + c * 256 + k0] =
        make_uint2(cvtpk(v.x, v.y), cvtpk(v.z, v.w));
  }
  __syncthreads();

  //---- Phase B: tp = te @ Ut + bt -> s_tpt (transposed, f32) ----
  {
    const int i = t >> 4, o = t & 15;
    const int off = o * 2;
    const int aa = off >> 3, p0 = off & 7;
    float acc0 = bt[off], acc1 = bt[off + 1];
    #pragma unroll
    for (int k = 0; k < 32; ++k) {
      float tv = s_red[i * 33 + k];
      float2 u = *(const float2*)&Ut[k * 32 + off];
      acc0 = fmaf(tv, u.x, acc0);
      acc1 = fmaf(tv, u.y, acc1);
    }
    s_tpt[(aa * 9 + p0) * 32 + i]     = acc0;
    s_tpt[(aa * 9 + p0 + 1) * 32 + i] = acc1;
  }

  //---- Phase C: ch = nh @ U + bw -> s_ch. Waves: (m, c, nt) ----
  {
    const int c = (w >> 1) & 1, nt = w >> 2;
    const int a0 = nt * 2, a1 = nt * 2 + 1;
    f32x4 acc0 = {0.f, 0.f, 0.f, 0.f}, acc1 = {0.f, 0.f, 0.f, 0.f};
    #pragma unroll
    for (int kt = 0; kt < 8; ++kt) {
      bf16x8 A = *(const bf16x8*)&s_u[(m * 16 + rl) * 520 + c * 256 + kt * 32 + 8 * q];
      bf16x8 B0 = *(const bf16x8*)&UcTf[(((c * 4 + a0) * 8 + kt) * 64 + l) * 8];
      bf16x8 B1 = *(const bf16x8*)&UcTf[(((c * 4 + a1) * 8 + kt) * 64 + l) * 8];
      acc0 = __builtin_amdgcn_mfma_f32_16x16x32_bf16(A, B0, acc0, 0, 0, 0);
      acc1 = __builtin_amdgcn_mfma_f32_16x16x32_bf16(A, B1, acc1, 0, 0, 0);
    }
    const float bias0 = bw[(c * 4 + a0) * 16 + rl];
    const float bias1 = bw[(c * 4 + a1) * 16 + rl];
    #pragma unroll
    for (int reg = 0; reg < 4; ++reg) {
      const int row = m * 16 + 4 * q + reg;
      s_ch[row * 164 + c * 80 + a0 * 20 + rl] = f2b(acc0[reg] + bias0);
      s_ch[row * 164 + c * 80 + a1 * 20 + rl] = f2b(acc1[reg] + bias1);
    }
  }
  __syncthreads();   // s_ch, s_tpt ready; nh reads done (s_u reusable)

  //---- Core a-loop ----
  const int ks = w >> 1;                       // k-split: kt {0-2},{3-5},{6-7},{8-9}
  const int kt0 = (ks < 2) ? ks * 3 : 6 + (ks - 2) * 2;
  const int ktn = (ks < 2) ? 3 : 2;

  for (int a = 0; a < 4; ++a) {
    //-- O-build: unit (row, qv), O[row][qv*18 + r] = h1[qv]*h2[r], r=0..17 --
    for (int lp = t; lp < 576; lp += NTHR) {
      const int row = lp & 31, qv = lp >> 5;   // qv 0..17 (17: h1 sentinel=0)
      const float h1f = b2f(s_ch[row * 164 + a * 20 + qv]);
      const u16* h2p = &s_ch[row * 164 + 80 + a * 20];
      uint2 ha = *(const uint2*)&h2p[0];
      uint2 hb = *(const uint2*)&h2p[4];
      uint2 hc = *(const uint2*)&h2p[8];
      uint2 hd = *(const uint2*)&h2p[12];
      unsigned he = *(const unsigned*)&h2p[16];
      unsigned* op = (unsigned*)&s_u[row * 328 + qv * 18];
      op[0] = cvtpk(h1f * blo(ha.x), h1f * bhi(ha.x));
      op[1] = cvtpk(h1f * blo(ha.y), h1f * bhi(ha.y));
      op[2] = cvtpk(h1f * blo(hb.x), h1f * bhi(hb.x));
      op[3] = cvtpk(h1f * blo(hb.y), h1f * bhi(hb.y));
      op[4] = cvtpk(h1f * blo(hc.x), h1f * bhi(hc.x));
      op[5] = cvtpk(h1f * blo(hc.y), h1f * bhi(hc.y));
      op[6] = cvtpk(h1f * blo(hd.x), h1f * bhi(hd.x));
      op[7] = cvtpk(h1f * blo(hd.y), h1f * bhi(hd.y));
      op[8] = cvtpk(h1f * blo(he),   h1f * bhi(he));
    }
    __syncthreads();

    //-- GEMM vs BTf (k-split) + h0 epilogue --
    f32x4 acc[9];
    #pragma unroll
    for (int p = 0; p < 9; ++p) acc[p] = (f32x4){0.f, 0.f, 0.f, 0.f};
    for (int kk = 0; kk < ktn; ++kk) {
      const int kt = kt0 + kk;
      bf16x8 A = *(const bf16x8*)&s_u[(m * 16 + rl) * 328 + kt * 32 + 8 * q];
      const u16* bp = &BTf[(size_t)a * 46080 + (size_t)kt * 512 + l * 8];
      #pragma unroll
      for (int p = 0; p < 9; ++p) {
        bf16x8 B = *(const bf16x8*)(bp + p * 5120);
        acc[p] = __builtin_amdgcn_mfma_f32_16x16x32_bf16(A, B, acc[p], 0, 0, 0);
      }
    }
    float gp[4] = {0.f, 0.f, 0.f, 0.f};
    #pragma unroll
    for (int p = 0; p < 9; ++p) {
      f4 tv = *(const f4*)&s_tpt[(a * 9 + p) * 32 + m * 16 + 4 * q];
      gp[0] = fmaf(tv.x, acc[p][0], gp[0]);
      gp[1] = fmaf(tv.y, acc[p][1], gp[1]);
      gp[2] = fmaf(tv.z, acc[p][2], gp[2]);
      gp[3] = fmaf(tv.w, acc[p][3], gp[3]);
    }
    if (ks) {
      #pragma unroll
      for (int reg = 0; reg < 4; ++reg)
        s_red[(ks - 1) * 544 + m * 272 + (4 * q + reg) * 17 + rl] = gp[reg];
    }
    __syncthreads();

    if (ks == 0) {
      #pragma unroll
      for (int reg = 0; reg < 4; ++reg) {
        const int idx = m * 272 + (4 * q + reg) * 17 + rl;
        float g = gp[reg] + s_red[idx] + s_red[544 + idx] + s_red[1088 + idx];
        const int row = m * 16 + 4 * q + reg;
        s_g[row * 136 + a * 32 + rl]      = f2b(g);
        s_g[row * 136 + a * 32 + 16 + rl] = 0;
      }
    }
  }
  __syncthreads();   // s_g ready for all waves

  //---- Phase E: out = g @ U_output + b_output. Waves: (m, e) ----
  {
    const int e = w >> 1;
    #pragma unroll
    for (int a = 0; a < 4; ++a) {
      bf16x8 A = *(const bf16x8*)&s_g[(m * 16 + rl) * 136 + a * 32 + 8 * q];
      #pragma unroll
      for (int j = 0; j < 4; ++j) {
        const int ht = e * 4 + j;
        bf16x8 B = *(const bf16x8*)&UOTf[((a * 16 + ht) * 64 + l) * 8];
        const float bias = bO[a * 256 + ht * 16 + rl];
        f32x4 accE = {bias, bias, bias, bias};
        accE = __builtin_amdgcn_mfma_f32_16x16x32_bf16(A, B, accE, 0, 0, 0);
        #pragma unroll
        for (int reg = 0; reg < 4; ++reg)
          out[(size_t)(ib0 + m * 16 + 4 * q + reg) * 1024 + a * 256 + ht * 16 + rl] =
              accE[reg];
      }
    }
  }
}

extern "C" void kernel_launch(void* const* d_in, const int* in_sizes, int n_in,
                              void* d_out, int out_size, void* d_ws, size_t ws_size,
                              hipStream_t stream) {
  const float* nh = (const float*)d_in[0];
  const float* te = (const float*)d_in[1];
  const float* U  = (const float*)d_in[2];
  const float* bw = (const float*)d_in[3];
  const float* Ut = (const float*)d_in[4];
  const float* bt = (const float*)d_in[5];
  const float* T  = (const float*)d_in[6];
  const float* UO = (const float*)d_in[7];
  const float* bO = (const float*)d_in[8];
  float* out = (float*)d_out;

  unsigned* ws32 = (unsigned*)d_ws;
  hipLaunchKernelGGL(hosvd_prep, dim3(488), dim3(256), 0, stream, U, T, UO, ws32);

  const u16* BTf  = (const u16*)d_ws;         // 184320 u16
  const u16* UcTf = BTf + 184320;             // 32768 u16
  const u16* UOTf = UcTf + 32768;             // 32768 u16

  const int bs = in_sizes[0] / 512;           // (BS,2,256)
  hipLaunchKernelGGL(hosvd_main, dim3(bs / TB), dim3(NTHR), 0, stream,
                     nh, te, bw, Ut, bt, bO, BTf, UcTf, UOTf, out);
}

// Round 5
// 48.144 us; speedup vs baseline: 2.1813x; 1.1997x over previous
//
#include <hip/hip_runtime.h>

#define NTHR 512
#define TB 32

typedef __attribute__((ext_vector_type(8))) short bf16x8;
typedef __attribute__((ext_vector_type(4))) float f32x4;
typedef float4 f4;
typedef unsigned short u16;

__device__ __forceinline__ u16 f2b(float x) {
  union { float f; unsigned u; } v; v.f = x;
  unsigned r = (v.u + 0x7fffu + ((v.u >> 16) & 1u)) >> 16;
  return (u16)r;
}
__device__ __forceinline__ float b2f(u16 u) {
  union { unsigned u; float f; } v; v.u = ((unsigned)u) << 16;
  return v.f;
}
__device__ __forceinline__ unsigned pack2(float a, float b) {
  return (unsigned)f2b(a) | ((unsigned)f2b(b) << 16);
}
__device__ __forceinline__ unsigned cvtpk(float lo, float hi) {
  unsigned r;
  asm("v_cvt_pk_bf16_f32 %0, %1, %2" : "=v"(r) : "v"(lo), "v"(hi));
  return r;
}
__device__ __forceinline__ float blo(unsigned u) {
  union { unsigned u; float f; } v; v.u = u << 16; return v.f;
}
__device__ __forceinline__ float bhi(unsigned u) {
  union { unsigned u; float f; } v; v.u = u & 0xffff0000u; return v.f;
}

// ---------------- prep: MFMA-fragment-ordered bf16 weights in ws ----------------
// BTf : frag_id = (a*9+p)*10+kt, lane l, 8 k's. k' = kt*32+(l>>4)*8+j, col s = l&15.
//       k' = q*18+r mapping; k'>=306 or r==17 -> 0.
// UcTf: frag_id = (c*4+a)*8+kt;  k = kt*32+(l>>4)*8+j, col r = l&15.
// UOTf: frag_id = a*16+ht;       k = (l>>4)*8+j (k>=16 -> 0), col h = ht*16+(l&15).
extern "C" __global__ void hosvd_prep(const float* __restrict__ U,
                                      const float* __restrict__ T,
                                      const float* __restrict__ UO,
                                      unsigned* __restrict__ ws32) {
  int id = blockIdx.x * 256 + threadIdx.x;
  if (id < 92160) {                       // BTf: 23040 frags * 4 u32
    int j2 = id & 3, frag = id >> 2;
    int l = frag & 63, f2 = frag >> 6;
    int kt = f2 % 10, ap = f2 / 10;
    int p = ap % 9, a = ap / 9;
    int s = l & 15;
    float v[2];
    #pragma unroll
    for (int j = 0; j < 2; ++j) {
      int kp = kt * 32 + (l >> 4) * 8 + j2 * 2 + j;
      float x = 0.f;
      if (kp < 306) {
        int q = (unsigned)kp / 18u, r = kp - q * 18;
        if (r < 17) x = T[(((a * 9 + p) * 17 + q) * 17 + r) * 16 + s];
      }
      v[j] = x;
    }
    ws32[id] = pack2(v[0], v[1]);
  } else if (id < 108544) {               // UcTf: 4096 frags * 4 u32
    int rel = id - 92160;
    int j2 = rel & 3, frag = rel >> 2;
    int l = frag & 63, f2 = frag >> 6;
    int kt = f2 & 7, g = f2 >> 3;
    int a = g & 3, c = g >> 2;
    int rr = l & 15;
    int k = kt * 32 + (l >> 4) * 8 + j2 * 2;
    float v0 = U[((c * 4 + a) * 256 + k + 0) * 16 + rr];
    float v1 = U[((c * 4 + a) * 256 + k + 1) * 16 + rr];
    ws32[id] = pack2(v0, v1);
  } else if (id < 124928) {               // UOTf: 4096 frags * 4 u32
    int rel = id - 108544;
    int j2 = rel & 3, frag = rel >> 2;
    int l = frag & 63, f2 = frag >> 6;
    int ht = f2 & 15, a = f2 >> 4;
    int h = ht * 16 + (l & 15);
    int k = (l >> 4) * 8 + j2 * 2;
    float v0 = (k + 0 < 16) ? UO[(a * 16 + k + 0) * 256 + h] : 0.f;
    float v1 = (k + 1 < 16) ? UO[(a * 16 + k + 1) * 256 + h] : 0.f;
    ws32[id] = pack2(v0, v1);
  }
}

// ---------------- main fused kernel ----------------
// LDS (75008 B -> 2 blocks/CU):
//  s_u   [20992] u16: nh [32][520] (early) | O [aL][32][328] (k'=q*18+r)
//  s_ch  [32][164] u16: h[row][c*80 + a*20 + idx]; idx16=1.0, idx17=0 sentinels
//  s_tpt [36][32] f32: tp transposed [a*9+p][row]; p=8 row = 1.0 sentinel
//  s_g   [32][136] u16: [row][a*32 + s]; slots 16..31 zero (K-pad for phase E)
//  s_red [2304] f32: te stage [32][33] (early) | k-split reduce, dbuf 2x1152
extern "C" __global__ __launch_bounds__(NTHR, 4)
void hosvd_main(const float* __restrict__ nh, const float* __restrict__ te,
                const float* __restrict__ bw, const float* __restrict__ Ut,
                const float* __restrict__ bt, const float* __restrict__ bO,
                const u16* __restrict__ BTf, const u16* __restrict__ UcTf,
                const u16* __restrict__ UOTf, float* __restrict__ out) {
  __shared__ __align__(16) u16   s_u[20992];
  __shared__ __align__(16) u16   s_ch[TB * 164];
  __shared__ __align__(16) float s_tpt[36 * 32];
  __shared__ __align__(16) u16   s_g[TB * 136];
  __shared__ __align__(16) float s_red[2304];

  const int t = threadIdx.x;
  const int ib0 = blockIdx.x * TB;
  const int w = t >> 6, l = t & 63;
  const int rl = l & 15, q = l >> 4;
  const int m = w & 1;
  const int aL = (w >> 1) & 1;    // core: aggregator within pair
  const int kh = w >> 2;          // core: k-half (kt 0-4 / 5-9)

  //---- sentinels ----
  {  // s_ch: h[16]=1.0, h[17]=0 for every (row, c, a)  (exactly 512 slots)
    const int row = t >> 4, cc = (t >> 3) & 1, aa = (t >> 1) & 3, sl = t & 1;
    s_ch[row * 164 + cc * 80 + aa * 20 + 16 + sl] = sl ? (u16)0 : (u16)0x3F80;
  }
  if (t < 128) {  // s_tpt p=8 row = 1.0
    const int aa = t >> 5, row = t & 31;
    s_tpt[(aa * 9 + 8) * 32 + row] = 1.0f;
  }

  //---- stage te -> s_red[32][33], nh -> s_u bf16 [32][520] ----
  if (t < 256) {
    const int row = t >> 3, k4 = t & 7;
    f4 v = *(const f4*)&te[(size_t)(ib0 + row) * 32 + k4 * 4];
    float* d = &s_red[row * 33 + k4 * 4];
    d[0] = v.x; d[1] = v.y; d[2] = v.z; d[3] = v.w;
  }
  for (int lp = t; lp < 4096; lp += NTHR) {
    const int row = lp >> 7, rem = lp & 127;
    const int c = rem >> 6, k0 = (rem & 63) * 4;
    f4 v = *(const f4*)&nh[((size_t)(ib0 + row) * 2 + c) * 256 + k0];
    *(uint2*)&s_u[row * 520 + c * 256 + k0] =
        make_uint2(cvtpk(v.x, v.y), cvtpk(v.z, v.w));
  }
  __syncthreads();

  //---- Phase B: tp = te @ Ut + bt -> s_tpt (transposed, f32) ----
  {
    const int i = t >> 4, o = t & 15;
    const int off = o * 2;
    const int aa = off >> 3, p0 = off & 7;
    float acc0 = bt[off], acc1 = bt[off + 1];
    #pragma unroll
    for (int k = 0; k < 32; ++k) {
      float tv = s_red[i * 33 + k];
      float2 u = *(const float2*)&Ut[k * 32 + off];
      acc0 = fmaf(tv, u.x, acc0);
      acc1 = fmaf(tv, u.y, acc1);
    }
    s_tpt[(aa * 9 + p0) * 32 + i]     = acc0;
    s_tpt[(aa * 9 + p0 + 1) * 32 + i] = acc1;
  }

  //---- Phase C: ch = nh @ U + bw -> s_ch. Waves: (m, c, nt) ----
  {
    const int c = (w >> 1) & 1, nt = w >> 2;
    const int a0 = nt * 2, a1 = nt * 2 + 1;
    f32x4 acc0 = {0.f, 0.f, 0.f, 0.f}, acc1 = {0.f, 0.f, 0.f, 0.f};
    #pragma unroll
    for (int kt = 0; kt < 8; ++kt) {
      bf16x8 A = *(const bf16x8*)&s_u[(m * 16 + rl) * 520 + c * 256 + kt * 32 + 8 * q];
      bf16x8 B0 = *(const bf16x8*)&UcTf[(((c * 4 + a0) * 8 + kt) * 64 + l) * 8];
      bf16x8 B1 = *(const bf16x8*)&UcTf[(((c * 4 + a1) * 8 + kt) * 64 + l) * 8];
      acc0 = __builtin_amdgcn_mfma_f32_16x16x32_bf16(A, B0, acc0, 0, 0, 0);
      acc1 = __builtin_amdgcn_mfma_f32_16x16x32_bf16(A, B1, acc1, 0, 0, 0);
    }
    const float bias0 = bw[(c * 4 + a0) * 16 + rl];
    const float bias1 = bw[(c * 4 + a1) * 16 + rl];
    #pragma unroll
    for (int reg = 0; reg < 4; ++reg) {
      const int row = m * 16 + 4 * q + reg;
      s_ch[row * 164 + c * 80 + a0 * 20 + rl] = f2b(acc0[reg] + bias0);
      s_ch[row * 164 + c * 80 + a1 * 20 + rl] = f2b(acc1[reg] + bias1);
    }
  }
  __syncthreads();   // s_ch, s_tpt ready; nh reads done (s_u reusable)

  //---- Core: 2 a-pair iterations; wave = (m, aL, kh) ----
  for (int it = 0; it < 2; ++it) {
    const int aB = it * 2;

    //-- O-build for BOTH aggregators of the pair: 1152 units (row, aLb, qv) --
    for (int lp = t; lp < 1152; lp += NTHR) {
      const int row = lp & 31, rest = lp >> 5;      // rest 0..35
      const int aLb = (rest >= 18) ? 1 : 0;
      const int qv = rest - aLb * 18;               // 0..17 (17: h1 sentinel=0)
      const int a = aB + aLb;
      const float h1f = b2f(s_ch[row * 164 + a * 20 + qv]);
      const u16* h2p = &s_ch[row * 164 + 80 + a * 20];
      uint2 ha = *(const uint2*)&h2p[0];
      uint2 hb = *(const uint2*)&h2p[4];
      uint2 hc = *(const uint2*)&h2p[8];
      uint2 hd = *(const uint2*)&h2p[12];
      unsigned he = *(const unsigned*)&h2p[16];
      unsigned* op = (unsigned*)&s_u[aLb * 10496 + row * 328 + qv * 18];
      op[0] = cvtpk(h1f * blo(ha.x), h1f * bhi(ha.x));
      op[1] = cvtpk(h1f * blo(ha.y), h1f * bhi(ha.y));
      op[2] = cvtpk(h1f * blo(hb.x), h1f * bhi(hb.x));
      op[3] = cvtpk(h1f * blo(hb.y), h1f * bhi(hb.y));
      op[4] = cvtpk(h1f * blo(hc.x), h1f * bhi(hc.x));
      op[5] = cvtpk(h1f * blo(hc.y), h1f * bhi(hc.y));
      op[6] = cvtpk(h1f * blo(hd.x), h1f * bhi(hd.x));
      op[7] = cvtpk(h1f * blo(hd.y), h1f * bhi(hd.y));
      op[8] = cvtpk(h1f * blo(he),   h1f * bhi(he));
    }
    __syncthreads();

    //-- 45-MFMA burst: a = aB+aL, kt = kh*5 .. kh*5+4, all 9 p --
    const int a = aB + aL;
    f32x4 acc[9];
    #pragma unroll
    for (int p = 0; p < 9; ++p) acc[p] = (f32x4){0.f, 0.f, 0.f, 0.f};
    __builtin_amdgcn_s_setprio(1);
    #pragma unroll
    for (int kk = 0; kk < 5; ++kk) {
      const int kt = kh * 5 + kk;
      bf16x8 A = *(const bf16x8*)&s_u[aL * 10496 + (m * 16 + rl) * 328 + kt * 32 + 8 * q];
      const u16* bp = &BTf[(size_t)a * 46080 + (size_t)kt * 512 + l * 8];
      #pragma unroll
      for (int p = 0; p < 9; ++p) {
        bf16x8 B = *(const bf16x8*)(bp + p * 5120);
        acc[p] = __builtin_amdgcn_mfma_f32_16x16x32_bf16(A, B, acc[p], 0, 0, 0);
      }
    }
    __builtin_amdgcn_s_setprio(0);

    //-- h0-weighted epilogue (f32-exact; k-split commutes) --
    float gp[4] = {0.f, 0.f, 0.f, 0.f};
    #pragma unroll
    for (int p = 0; p < 9; ++p) {
      f4 tv = *(const f4*)&s_tpt[(a * 9 + p) * 32 + m * 16 + 4 * q];
      gp[0] = fmaf(tv.x, acc[p][0], gp[0]);
      gp[1] = fmaf(tv.y, acc[p][1], gp[1]);
      gp[2] = fmaf(tv.z, acc[p][2], gp[2]);
      gp[3] = fmaf(tv.w, acc[p][3], gp[3]);
    }
    if (kh == 1) {
      #pragma unroll
      for (int reg = 0; reg < 4; ++reg)
        s_red[it * 1152 + (m * 2 + aL) * 272 + (4 * q + reg) * 17 + rl] = gp[reg];
    }
    __syncthreads();

    if (kh == 0) {
      #pragma unroll
      for (int reg = 0; reg < 4; ++reg) {
        float g = gp[reg] +
                  s_red[it * 1152 + (m * 2 + aL) * 272 + (4 * q + reg) * 17 + rl];
        const int row = m * 16 + 4 * q + reg;
        s_g[row * 136 + a * 32 + rl]      = f2b(g);
        s_g[row * 136 + a * 32 + 16 + rl] = 0;
      }
    }
  }
  __syncthreads();   // s_g ready for all waves

  //---- Phase E: out = g @ U_output + b_output. Waves: (m, e) ----
  {
    const int e = w >> 1;
    #pragma unroll
    for (int a = 0; a < 4; ++a) {
      bf16x8 A = *(const bf16x8*)&s_g[(m * 16 + rl) * 136 + a * 32 + 8 * q];
      #pragma unroll
      for (int j = 0; j < 4; ++j) {
        const int ht = e * 4 + j;
        bf16x8 B = *(const bf16x8*)&UOTf[((a * 16 + ht) * 64 + l) * 8];
        const float bias = bO[a * 256 + ht * 16 + rl];
        f32x4 accE = {bias, bias, bias, bias};
        accE = __builtin_amdgcn_mfma_f32_16x16x32_bf16(A, B, accE, 0, 0, 0);
        #pragma unroll
        for (int reg = 0; reg < 4; ++reg)
          out[(size_t)(ib0 + m * 16 + 4 * q + reg) * 1024 + a * 256 + ht * 16 + rl] =
              accE[reg];
      }
    }
  }
}

extern "C" void kernel_launch(void* const* d_in, const int* in_sizes, int n_in,
                              void* d_out, int out_size, void* d_ws, size_t ws_size,
                              hipStream_t stream) {
  const float* nh = (const float*)d_in[0];
  const float* te = (const float*)d_in[1];
  const float* U  = (const float*)d_in[2];
  const float* bw = (const float*)d_in[3];
  const float* Ut = (const float*)d_in[4];
  const float* bt = (const float*)d_in[5];
  const float* T  = (const float*)d_in[6];
  const float* UO = (const float*)d_in[7];
  const float* bO = (const float*)d_in[8];
  float* out = (float*)d_out;

  unsigned* ws32 = (unsigned*)d_ws;
  hipLaunchKernelGGL(hosvd_prep, dim3(488), dim3(256), 0, stream, U, T, UO, ws32);

  const u16* BTf  = (const u16*)d_ws;         // 184320 u16
  const u16* UcTf = BTf + 184320;             // 32768 u16
  const u16* UOTf = UcTf + 32768;             // 32768 u16

  const int bs = in_sizes[0] / 512;           // (BS,2,256)
  hipLaunchKernelGGL(hosvd_main, dim3(bs / TB), dim3(NTHR), 0, stream,
                     nh, te, bw, Ut, bt, bO, BTf, UcTf, UOTf, out);
}

// Round 6
// 44.836 us; speedup vs baseline: 2.3422x; 1.0738x over previous
//
#include <hip/hip_runtime.h>

#define NTHR 512
#define TB 32

typedef __attribute__((ext_vector_type(8))) short bf16x8;
typedef __attribute__((ext_vector_type(4))) float f32x4;
typedef float4 f4;
typedef unsigned short u16;

__device__ __forceinline__ u16 f2b(float x) {
  union { float f; unsigned u; } v; v.f = x;
  unsigned r = (v.u + 0x7fffu + ((v.u >> 16) & 1u)) >> 16;
  return (u16)r;
}
__device__ __forceinline__ float b2f(u16 u) {
  union { unsigned u; float f; } v; v.u = ((unsigned)u) << 16;
  return v.f;
}
__device__ __forceinline__ unsigned pack2(float a, float b) {
  return (unsigned)f2b(a) | ((unsigned)f2b(b) << 16);
}
__device__ __forceinline__ unsigned cvtpk(float lo, float hi) {
  unsigned r;
  asm("v_cvt_pk_bf16_f32 %0, %1, %2" : "=v"(r) : "v"(lo), "v"(hi));
  return r;
}
__device__ __forceinline__ float blo(unsigned u) {
  union { unsigned u; float f; } v; v.u = u << 16; return v.f;
}
__device__ __forceinline__ float bhi(unsigned u) {
  union { unsigned u; float f; } v; v.u = u & 0xffff0000u; return v.f;
}

// ---------------- prep: MFMA-fragment-ordered bf16 weights in ws ----------------
// BTf : frag_id = (a*10+kt)*9+p  (9 p-frags contiguous per (a,kt) = 9KB block)
//       lane l, 8 k's: k' = kt*32+(l>>4)*8+j, col s = l&15; k'=q*18+r; pad->0
// UcTf: frag_id = (c*4+a)*8+kt;  k = kt*32+(l>>4)*8+j, col r = l&15.
// UOTf: frag_id = a*16+ht;       k = (l>>4)*8+j (k>=16 -> 0), col h = ht*16+(l&15).
extern "C" __global__ void hosvd_prep(const float* __restrict__ U,
                                      const float* __restrict__ T,
                                      const float* __restrict__ UO,
                                      unsigned* __restrict__ ws32) {
  int id = blockIdx.x * 256 + threadIdx.x;
  if (id < 92160) {                       // BTf: 23040 frags * 4 u32
    int j2 = id & 3, frag = id >> 2;
    int l = frag & 63, f2 = frag >> 6;    // f2 = (a*10+kt)*9+p
    int p = f2 % 9, akt = f2 / 9;
    int kt = akt % 10, a = akt / 10;
    int s = l & 15;
    float v[2];
    #pragma unroll
    for (int j = 0; j < 2; ++j) {
      int kp = kt * 32 + (l >> 4) * 8 + j2 * 2 + j;
      float x = 0.f;
      if (kp < 306) {
        int q = (unsigned)kp / 18u, r = kp - q * 18;
        if (r < 17) x = T[(((a * 9 + p) * 17 + q) * 17 + r) * 16 + s];
      }
      v[j] = x;
    }
    ws32[id] = pack2(v[0], v[1]);
  } else if (id < 108544) {               // UcTf: 4096 frags * 4 u32
    int rel = id - 92160;
    int j2 = rel & 3, frag = rel >> 2;
    int l = frag & 63, f2 = frag >> 6;
    int kt = f2 & 7, g = f2 >> 3;
    int a = g & 3, c = g >> 2;
    int rr = l & 15;
    int k = kt * 32 + (l >> 4) * 8 + j2 * 2;
    float v0 = U[((c * 4 + a) * 256 + k + 0) * 16 + rr];
    float v1 = U[((c * 4 + a) * 256 + k + 1) * 16 + rr];
    ws32[id] = pack2(v0, v1);
  } else if (id < 124928) {               // UOTf: 4096 frags * 4 u32
    int rel = id - 108544;
    int j2 = rel & 3, frag = rel >> 2;
    int l = frag & 63, f2 = frag >> 6;
    int ht = f2 & 15, a = f2 >> 4;
    int h = ht * 16 + (l & 15);
    int k = (l >> 4) * 8 + j2 * 2;
    float v0 = (k + 0 < 16) ? UO[(a * 16 + k + 0) * 256 + h] : 0.f;
    float v1 = (k + 1 < 16) ? UO[(a * 16 + k + 1) * 256 + h] : 0.f;
    ws32[id] = pack2(v0, v1);
  }
}

#define MFMA_B(A, B, C) __builtin_amdgcn_mfma_f32_16x16x32_bf16(A, B, C, 0, 0, 0)

// load 9 B frags (one kt, all p) into named locals — forces 9 loads in flight
#define LOADB(ktv)                                                          \
  do {                                                                      \
    const u16* bp_ = &BTf[(size_t)((a * 10 + (ktv)) * 9) * 512 + l * 8];    \
    Bv0 = *(const bf16x8*)(bp_ + 0 * 512);                                  \
    Bv1 = *(const bf16x8*)(bp_ + 1 * 512);                                  \
    Bv2 = *(const bf16x8*)(bp_ + 2 * 512);                                  \
    Bv3 = *(const bf16x8*)(bp_ + 3 * 512);                                  \
    Bv4 = *(const bf16x8*)(bp_ + 4 * 512);                                  \
    Bv5 = *(const bf16x8*)(bp_ + 5 * 512);                                  \
    Bv6 = *(const bf16x8*)(bp_ + 6 * 512);                                  \
    Bv7 = *(const bf16x8*)(bp_ + 7 * 512);                                  \
    Bv8 = *(const bf16x8*)(bp_ + 8 * 512);                                  \
  } while (0)

#define MFMA9(ktv)                                                          \
  do {                                                                      \
    bf16x8 A_ = *(const bf16x8*)&s_u[aL * 10496 + (m * 16 + rl) * 328 +     \
                                     (ktv) * 32 + 8 * q];                   \
    acc0 = MFMA_B(A_, Bv0, acc0);                                           \
    acc1 = MFMA_B(A_, Bv1, acc1);                                           \
    acc2 = MFMA_B(A_, Bv2, acc2);                                           \
    acc3 = MFMA_B(A_, Bv3, acc3);                                           \
    acc4 = MFMA_B(A_, Bv4, acc4);                                           \
    acc5 = MFMA_B(A_, Bv5, acc5);                                           \
    acc6 = MFMA_B(A_, Bv6, acc6);                                           \
    acc7 = MFMA_B(A_, Bv7, acc7);                                           \
    acc8 = MFMA_B(A_, Bv8, acc8);                                           \
  } while (0)

// ---------------- main fused kernel ----------------
// LDS (75008 B -> 2 blocks/CU):
//  s_u   [20992] u16: nh [32][520] (early) | O [aL][32][328] (k'=q*18+r)
//  s_ch  [32][164] u16: h[row][c*80 + a*20 + idx]; idx16=1.0, idx17=0 sentinels
//  s_tpt [36][32] f32: tp transposed [a*9+p][row]; p=8 row = 1.0 sentinel
//  s_g   [32][136] u16: [row][a*32 + s]; slots 16..31 zero (K-pad for phase E)
//  s_red [2304] f32: te stage [32][33] (early) | k-split reduce, dbuf 2x1152
extern "C" __global__ __launch_bounds__(NTHR, 4)
void hosvd_main(const float* __restrict__ nh, const float* __restrict__ te,
                const float* __restrict__ bw, const float* __restrict__ Ut,
                const float* __restrict__ bt, const float* __restrict__ bO,
                const u16* __restrict__ BTf, const u16* __restrict__ UcTf,
                const u16* __restrict__ UOTf, float* __restrict__ out) {
  __shared__ __align__(16) u16   s_u[20992];
  __shared__ __align__(16) u16   s_ch[TB * 164];
  __shared__ __align__(16) float s_tpt[36 * 32];
  __shared__ __align__(16) u16   s_g[TB * 136];
  __shared__ __align__(16) float s_red[2304];

  const int t = threadIdx.x;
  const int ib0 = blockIdx.x * TB;
  const int w = t >> 6, l = t & 63;
  const int rl = l & 15, q = l >> 4;
  const int m = w & 1;
  const int aL = (w >> 1) & 1;    // core: aggregator within pair
  const int kh = w >> 2;          // core: k-half (kt 0-4 / 5-9)

  //---- sentinels ----
  {  // s_ch: h[16]=1.0, h[17]=0 for every (row, c, a)  (exactly 512 slots)
    const int row = t >> 4, cc = (t >> 3) & 1, aa = (t >> 1) & 3, sl = t & 1;
    s_ch[row * 164 + cc * 80 + aa * 20 + 16 + sl] = sl ? (u16)0 : (u16)0x3F80;
  }
  if (t < 128) {  // s_tpt p=8 row = 1.0
    const int aa = t >> 5, row = t & 31;
    s_tpt[(aa * 9 + 8) * 32 + row] = 1.0f;
  }

  //---- stage te -> s_red[32][33], nh -> s_u bf16 [32][520] ----
  if (t < 256) {
    const int row = t >> 3, k4 = t & 7;
    f4 v = *(const f4*)&te[(size_t)(ib0 + row) * 32 + k4 * 4];
    float* d = &s_red[row * 33 + k4 * 4];
    d[0] = v.x; d[1] = v.y; d[2] = v.z; d[3] = v.w;
  }
  for (int lp = t; lp < 4096; lp += NTHR) {
    const int row = lp >> 7, rem = lp & 127;
    const int c = rem >> 6, k0 = (rem & 63) * 4;
    f4 v = *(const f4*)&nh[((size_t)(ib0 + row) * 2 + c) * 256 + k0];
    *(uint2*)&s_u[row * 520 + c * 256 + k0] =
        make_uint2(cvtpk(v.x, v.y), cvtpk(v.z, v.w));
  }
  __syncthreads();

  //---- Phase B: tp = te @ Ut + bt -> s_tpt (transposed, f32) ----
  {
    const int i = t >> 4, o = t & 15;
    const int off = o * 2;
    const int aa = off >> 3, p0 = off & 7;
    float acc0 = bt[off], acc1 = bt[off + 1];
    #pragma unroll
    for (int k = 0; k < 32; ++k) {
      float tv = s_red[i * 33 + k];
      float2 u = *(const float2*)&Ut[k * 32 + off];
      acc0 = fmaf(tv, u.x, acc0);
      acc1 = fmaf(tv, u.y, acc1);
    }
    s_tpt[(aa * 9 + p0) * 32 + i]     = acc0;
    s_tpt[(aa * 9 + p0 + 1) * 32 + i] = acc1;
  }

  //---- Phase C: ch = nh @ U + bw -> s_ch. Waves: (m, c, nt) ----
  {
    const int c = (w >> 1) & 1, nt = w >> 2;
    const int a0 = nt * 2, a1 = nt * 2 + 1;
    const u16* u0 = &UcTf[((size_t)((c * 4 + a0) * 8) * 64 + l) * 8];
    const u16* u1 = &UcTf[((size_t)((c * 4 + a1) * 8) * 64 + l) * 8];
    f32x4 acc0 = {0.f, 0.f, 0.f, 0.f}, acc1 = {0.f, 0.f, 0.f, 0.f};
    #define PC_HALF(KT0)                                                        \
    {                                                                           \
      bf16x8 Ca = *(const bf16x8*)(u0 + (KT0 + 0) * 512);                       \
      bf16x8 Cb = *(const bf16x8*)(u1 + (KT0 + 0) * 512);                       \
      bf16x8 Cc = *(const bf16x8*)(u0 + (KT0 + 1) * 512);                       \
      bf16x8 Cd = *(const bf16x8*)(u1 + (KT0 + 1) * 512);                       \
      bf16x8 Ce = *(const bf16x8*)(u0 + (KT0 + 2) * 512);                       \
      bf16x8 Cf = *(const bf16x8*)(u1 + (KT0 + 2) * 512);                       \
      bf16x8 Cg = *(const bf16x8*)(u0 + (KT0 + 3) * 512);                       \
      bf16x8 Ch = *(const bf16x8*)(u1 + (KT0 + 3) * 512);                       \
      bf16x8 A0 = *(const bf16x8*)&s_u[(m * 16 + rl) * 520 + c * 256 + (KT0 + 0) * 32 + 8 * q]; \
      bf16x8 A1 = *(const bf16x8*)&s_u[(m * 16 + rl) * 520 + c * 256 + (KT0 + 1) * 32 + 8 * q]; \
      bf16x8 A2 = *(const bf16x8*)&s_u[(m * 16 + rl) * 520 + c * 256 + (KT0 + 2) * 32 + 8 * q]; \
      bf16x8 A3 = *(const bf16x8*)&s_u[(m * 16 + rl) * 520 + c * 256 + (KT0 + 3) * 32 + 8 * q]; \
      acc0 = MFMA_B(A0, Ca, acc0); acc1 = MFMA_B(A0, Cb, acc1);                 \
      acc0 = MFMA_B(A1, Cc, acc0); acc1 = MFMA_B(A1, Cd, acc1);                 \
      acc0 = MFMA_B(A2, Ce, acc0); acc1 = MFMA_B(A2, Cf, acc1);                 \
      acc0 = MFMA_B(A3, Cg, acc0); acc1 = MFMA_B(A3, Ch, acc1);                 \
    }
    PC_HALF(0)
    PC_HALF(4)
    #undef PC_HALF
    const float bias0 = bw[(c * 4 + a0) * 16 + rl];
    const float bias1 = bw[(c * 4 + a1) * 16 + rl];
    #pragma unroll
    for (int reg = 0; reg < 4; ++reg) {
      const int row = m * 16 + 4 * q + reg;
      s_ch[row * 164 + c * 80 + a0 * 20 + rl] = f2b(acc0[reg] + bias0);
      s_ch[row * 164 + c * 80 + a1 * 20 + rl] = f2b(acc1[reg] + bias1);
    }
  }
  __syncthreads();   // s_ch, s_tpt ready; nh reads done (s_u reusable)

  //---- Core: 2 a-pair iterations; wave = (m, aL, kh) ----
  for (int it = 0; it < 2; ++it) {
    const int aB = it * 2;
    const int a = aB + aL;

    // prefetch first kt's 9 B frags (independent of LDS) — hides under O-build
    bf16x8 Bv0, Bv1, Bv2, Bv3, Bv4, Bv5, Bv6, Bv7, Bv8;
    LOADB(kh * 5);

    //-- O-build for BOTH aggregators of the pair: 1152 units (row, aLb, qv) --
    for (int lp = t; lp < 1152; lp += NTHR) {
      const int row = lp & 31, rest = lp >> 5;      // rest 0..35
      const int aLb = (rest >= 18) ? 1 : 0;
      const int qv = rest - aLb * 18;               // 0..17 (17: h1 sentinel=0)
      const int ab = aB + aLb;
      const float h1f = b2f(s_ch[row * 164 + ab * 20 + qv]);
      const u16* h2p = &s_ch[row * 164 + 80 + ab * 20];
      uint2 ha = *(const uint2*)&h2p[0];
      uint2 hb = *(const uint2*)&h2p[4];
      uint2 hc = *(const uint2*)&h2p[8];
      uint2 hd = *(const uint2*)&h2p[12];
      unsigned he = *(const unsigned*)&h2p[16];
      unsigned* op = (unsigned*)&s_u[aLb * 10496 + row * 328 + qv * 18];
      op[0] = cvtpk(h1f * blo(ha.x), h1f * bhi(ha.x));
      op[1] = cvtpk(h1f * blo(ha.y), h1f * bhi(ha.y));
      op[2] = cvtpk(h1f * blo(hb.x), h1f * bhi(hb.x));
      op[3] = cvtpk(h1f * blo(hb.y), h1f * bhi(hb.y));
      op[4] = cvtpk(h1f * blo(hc.x), h1f * bhi(hc.x));
      op[5] = cvtpk(h1f * blo(hc.y), h1f * bhi(hc.y));
      op[6] = cvtpk(h1f * blo(hd.x), h1f * bhi(hd.x));
      op[7] = cvtpk(h1f * blo(hd.y), h1f * bhi(hd.y));
      op[8] = cvtpk(h1f * blo(he),   h1f * bhi(he));
    }
    __syncthreads();

    //-- 45-MFMA burst: 9 loads in flight per kt, batch-then-MFMA --
    f32x4 acc0 = {0.f, 0.f, 0.f, 0.f}, acc1 = acc0, acc2 = acc0, acc3 = acc0,
          acc4 = acc0, acc5 = acc0, acc6 = acc0, acc7 = acc0, acc8 = acc0;
    __builtin_amdgcn_s_setprio(1);
    MFMA9(kh * 5 + 0);
    LOADB(kh * 5 + 1); MFMA9(kh * 5 + 1);
    LOADB(kh * 5 + 2); MFMA9(kh * 5 + 2);
    LOADB(kh * 5 + 3); MFMA9(kh * 5 + 3);
    LOADB(kh * 5 + 4); MFMA9(kh * 5 + 4);
    __builtin_amdgcn_s_setprio(0);

    //-- h0-weighted epilogue (f32-exact; k-split commutes) --
    float gp[4] = {0.f, 0.f, 0.f, 0.f};
    {
      f4 tv;
      #define EPI(PP, ACC)                                              \
        tv = *(const f4*)&s_tpt[(a * 9 + PP) * 32 + m * 16 + 4 * q];    \
        gp[0] = fmaf(tv.x, ACC[0], gp[0]);                              \
        gp[1] = fmaf(tv.y, ACC[1], gp[1]);                              \
        gp[2] = fmaf(tv.z, ACC[2], gp[2]);                              \
        gp[3] = fmaf(tv.w, ACC[3], gp[3]);
      EPI(0, acc0) EPI(1, acc1) EPI(2, acc2) EPI(3, acc3) EPI(4, acc4)
      EPI(5, acc5) EPI(6, acc6) EPI(7, acc7) EPI(8, acc8)
      #undef EPI
    }
    if (kh == 1) {
      #pragma unroll
      for (int reg = 0; reg < 4; ++reg)
        s_red[it * 1152 + (m * 2 + aL) * 272 + (4 * q + reg) * 17 + rl] = gp[reg];
    }
    __syncthreads();

    if (kh == 0) {
      #pragma unroll
      for (int reg = 0; reg < 4; ++reg) {
        float g = gp[reg] +
                  s_red[it * 1152 + (m * 2 + aL) * 272 + (4 * q + reg) * 17 + rl];
        const int row = m * 16 + 4 * q + reg;
        s_g[row * 136 + a * 32 + rl]      = f2b(g);
        s_g[row * 136 + a * 32 + 16 + rl] = 0;
      }
    }
  }
  __syncthreads();   // s_g ready for all waves

  //---- Phase E: out = g @ U_output + b_output. Waves: (m, e) ----
  {
    const int e = w >> 1;
    #pragma unroll
    for (int a = 0; a < 4; ++a) {
      const u16* ub = &UOTf[((size_t)(a * 16 + e * 4) * 64 + l) * 8];
      bf16x8 E0 = *(const bf16x8*)(ub + 0 * 512);
      bf16x8 E1 = *(const bf16x8*)(ub + 1 * 512);
      bf16x8 E2 = *(const bf16x8*)(ub + 2 * 512);
      bf16x8 E3 = *(const bf16x8*)(ub + 3 * 512);
      const float b0 = bO[a * 256 + (e * 4 + 0) * 16 + rl];
      const float b1 = bO[a * 256 + (e * 4 + 1) * 16 + rl];
      const float b2 = bO[a * 256 + (e * 4 + 2) * 16 + rl];
      const float b3 = bO[a * 256 + (e * 4 + 3) * 16 + rl];
      bf16x8 A = *(const bf16x8*)&s_g[(m * 16 + rl) * 136 + a * 32 + 8 * q];
      f32x4 e0 = {b0, b0, b0, b0}, e1 = {b1, b1, b1, b1};
      f32x4 e2 = {b2, b2, b2, b2}, e3 = {b3, b3, b3, b3};
      e0 = MFMA_B(A, E0, e0);
      e1 = MFMA_B(A, E1, e1);
      e2 = MFMA_B(A, E2, e2);
      e3 = MFMA_B(A, E3, e3);
      #pragma unroll
      for (int reg = 0; reg < 4; ++reg) {
        const size_t ro = (size_t)(ib0 + m * 16 + 4 * q + reg) * 1024 + a * 256;
        out[ro + (e * 4 + 0) * 16 + rl] = e0[reg];
        out[ro + (e * 4 + 1) * 16 + rl] = e1[reg];
        out[ro + (e * 4 + 2) * 16 + rl] = e2[reg];
        out[ro + (e * 4 + 3) * 16 + rl] = e3[reg];
      }
    }
  }
}

extern "C" void kernel_launch(void* const* d_in, const int* in_sizes, int n_in,
                              void* d_out, int out_size, void* d_ws, size_t ws_size,
                              hipStream_t stream) {
  const float* nh = (const float*)d_in[0];
  const float* te = (const float*)d_in[1];
  const float* U  = (const float*)d_in[2];
  const float* bw = (const float*)d_in[3];
  const float* Ut = (const float*)d_in[4];
  const float* bt = (const float*)d_in[5];
  const float* T  = (const float*)d_in[6];
  const float* UO = (const float*)d_in[7];
  const float* bO = (const float*)d_in[8];
  float* out = (float*)d_out;

  unsigned* ws32 = (unsigned*)d_ws;
  hipLaunchKernelGGL(hosvd_prep, dim3(488), dim3(256), 0, stream, U, T, UO, ws32);

  const u16* BTf  = (const u16*)d_ws;         // 184320 u16
  const u16* UcTf = BTf + 184320;             // 32768 u16
  const u16* UOTf = UcTf + 32768;             // 32768 u16

  const int bs = in_sizes[0] / 512;           // (BS,2,256)
  hipLaunchKernelGGL(hosvd_main, dim3(bs / TB), dim3(NTHR), 0, stream,
                     nh, te, bw, Ut, bt, bO, BTf, UcTf, UOTf, out);
}

// Round 7
// 42.586 us; speedup vs baseline: 2.4659x; 1.0528x over previous
//
#include <hip/hip_runtime.h>

#define NTHR 512
#define TB 32

typedef __attribute__((ext_vector_type(8))) short bf16x8;
typedef __attribute__((ext_vector_type(4))) float f32x4;
typedef float4 f4;
typedef unsigned short u16;

__device__ __forceinline__ u16 f2b(float x) {
  union { float f; unsigned u; } v; v.f = x;
  unsigned r = (v.u + 0x7fffu + ((v.u >> 16) & 1u)) >> 16;
  return (u16)r;
}
__device__ __forceinline__ float b2f(u16 u) {
  union { unsigned u; float f; } v; v.u = ((unsigned)u) << 16;
  return v.f;
}
__device__ __forceinline__ unsigned pack2(float a, float b) {
  return (unsigned)f2b(a) | ((unsigned)f2b(b) << 16);
}
__device__ __forceinline__ unsigned cvtpk(float lo, float hi) {
  unsigned r;
  asm("v_cvt_pk_bf16_f32 %0, %1, %2" : "=v"(r) : "v"(lo), "v"(hi));
  return r;
}
__device__ __forceinline__ float blo(unsigned u) {
  union { unsigned u; float f; } v; v.u = u << 16; return v.f;
}
__device__ __forceinline__ float bhi(unsigned u) {
  union { unsigned u; float f; } v; v.u = u & 0xffff0000u; return v.f;
}

// ---------------- prep: MFMA-fragment-ordered bf16 weights in ws ----------------
// BTf : frag_id = (a*10+kt)*9+p  (9 p-frags contiguous per (a,kt) = 9KB block)
//       lane l, 8 k's: k' = kt*32+(l>>4)*8+j, col s = l&15; k'=q*18+r; pad->0
// UcTf: frag_id = (c*4+a)*8+kt;  k = kt*32+(l>>4)*8+j, col r = l&15.
// UOTf: frag_id = a*16+ht;       k = (l>>4)*8+j (k>=16 -> 0), col h = ht*16+(l&15).
extern "C" __global__ void hosvd_prep(const float* __restrict__ U,
                                      const float* __restrict__ T,
                                      const float* __restrict__ UO,
                                      unsigned* __restrict__ ws32) {
  int id = blockIdx.x * 256 + threadIdx.x;
  if (id < 92160) {                       // BTf: 23040 frags * 4 u32
    int j2 = id & 3, frag = id >> 2;
    int l = frag & 63, f2 = frag >> 6;    // f2 = (a*10+kt)*9+p
    int p = f2 % 9, akt = f2 / 9;
    int kt = akt % 10, a = akt / 10;
    int s = l & 15;
    float v[2];
    #pragma unroll
    for (int j = 0; j < 2; ++j) {
      int kp = kt * 32 + (l >> 4) * 8 + j2 * 2 + j;
      float x = 0.f;
      if (kp < 306) {
        int q = (unsigned)kp / 18u, r = kp - q * 18;
        if (r < 17) x = T[(((a * 9 + p) * 17 + q) * 17 + r) * 16 + s];
      }
      v[j] = x;
    }
    ws32[id] = pack2(v[0], v[1]);
  } else if (id < 108544) {               // UcTf: 4096 frags * 4 u32
    int rel = id - 92160;
    int j2 = rel & 3, frag = rel >> 2;
    int l = frag & 63, f2 = frag >> 6;
    int kt = f2 & 7, g = f2 >> 3;
    int a = g & 3, c = g >> 2;
    int rr = l & 15;
    int k = kt * 32 + (l >> 4) * 8 + j2 * 2;
    float v0 = U[((c * 4 + a) * 256 + k + 0) * 16 + rr];
    float v1 = U[((c * 4 + a) * 256 + k + 1) * 16 + rr];
    ws32[id] = pack2(v0, v1);
  } else if (id < 124928) {               // UOTf: 4096 frags * 4 u32
    int rel = id - 108544;
    int j2 = rel & 3, frag = rel >> 2;
    int l = frag & 63, f2 = frag >> 6;
    int ht = f2 & 15, a = f2 >> 4;
    int h = ht * 16 + (l & 15);
    int k = (l >> 4) * 8 + j2 * 2;
    float v0 = (k + 0 < 16) ? UO[(a * 16 + k + 0) * 256 + h] : 0.f;
    float v1 = (k + 1 < 16) ? UO[(a * 16 + k + 1) * 256 + h] : 0.f;
    ws32[id] = pack2(v0, v1);
  }
}

#define MFMA_B(A, B, C) __builtin_amdgcn_mfma_f32_16x16x32_bf16(A, B, C, 0, 0, 0)

// load 9 B frags (one kt, all p) into named locals
#define LOADB(ktv)                                                          \
  do {                                                                      \
    const u16* bp_ = &BTf[(size_t)((a * 10 + (ktv)) * 9) * 512 + l * 8];    \
    Bv0 = *(const bf16x8*)(bp_ + 0 * 512);                                  \
    Bv1 = *(const bf16x8*)(bp_ + 1 * 512);                                  \
    Bv2 = *(const bf16x8*)(bp_ + 2 * 512);                                  \
    Bv3 = *(const bf16x8*)(bp_ + 3 * 512);                                  \
    Bv4 = *(const bf16x8*)(bp_ + 4 * 512);                                  \
    Bv5 = *(const bf16x8*)(bp_ + 5 * 512);                                  \
    Bv6 = *(const bf16x8*)(bp_ + 6 * 512);                                  \
    Bv7 = *(const bf16x8*)(bp_ + 7 * 512);                                  \
    Bv8 = *(const bf16x8*)(bp_ + 8 * 512);                                  \
  } while (0)

// 18 MFMAs: both m-tiles against the 9 resident B frags (2 MFMAs per B load)
#define MFMA18(ktv)                                                            \
  do {                                                                         \
    bf16x8 A0_ = *(const bf16x8*)&s_u[aL * 10496 + rl * 328 + (ktv) * 32 + 8 * q];        \
    bf16x8 A1_ = *(const bf16x8*)&s_u[aL * 10496 + (16 + rl) * 328 + (ktv) * 32 + 8 * q]; \
    acc[0][0] = MFMA_B(A0_, Bv0, acc[0][0]); acc[0][1] = MFMA_B(A1_, Bv0, acc[0][1]);     \
    acc[1][0] = MFMA_B(A0_, Bv1, acc[1][0]); acc[1][1] = MFMA_B(A1_, Bv1, acc[1][1]);     \
    acc[2][0] = MFMA_B(A0_, Bv2, acc[2][0]); acc[2][1] = MFMA_B(A1_, Bv2, acc[2][1]);     \
    acc[3][0] = MFMA_B(A0_, Bv3, acc[3][0]); acc[3][1] = MFMA_B(A1_, Bv3, acc[3][1]);     \
    acc[4][0] = MFMA_B(A0_, Bv4, acc[4][0]); acc[4][1] = MFMA_B(A1_, Bv4, acc[4][1]);     \
    acc[5][0] = MFMA_B(A0_, Bv5, acc[5][0]); acc[5][1] = MFMA_B(A1_, Bv5, acc[5][1]);     \
    acc[6][0] = MFMA_B(A0_, Bv6, acc[6][0]); acc[6][1] = MFMA_B(A1_, Bv6, acc[6][1]);     \
    acc[7][0] = MFMA_B(A0_, Bv7, acc[7][0]); acc[7][1] = MFMA_B(A1_, Bv7, acc[7][1]);     \
    acc[8][0] = MFMA_B(A0_, Bv8, acc[8][0]); acc[8][1] = MFMA_B(A1_, Bv8, acc[8][1]);     \
  } while (0)

// ---------------- main fused kernel ----------------
// LDS (78848 B -> 2 blocks/CU):
//  s_u   [20992] u16: nh [32][520] (early) | O [aL][32][328] (k'=q*18+r)
//  s_ch  [32][164] u16: h[row][c*80 + a*20 + idx]; idx16=1.0, idx17=0 sentinels
//  s_tpt [36][32] f32: tp transposed [a*9+p][row]; p=8 row = 1.0 sentinel
//  s_g   [32][136] u16: [row][a*32 + s]; slots 16..31 zero (K-pad for phase E)
//  s_red [3264] f32: te stage [32][33] (early) | 3-slice k-split reduce
extern "C" __global__ __launch_bounds__(NTHR, 4)
void hosvd_main(const float* __restrict__ nh, const float* __restrict__ te,
                const float* __restrict__ bw, const float* __restrict__ Ut,
                const float* __restrict__ bt, const float* __restrict__ bO,
                const u16* __restrict__ BTf, const u16* __restrict__ UcTf,
                const u16* __restrict__ UOTf, float* __restrict__ out) {
  __shared__ __align__(16) u16   s_u[20992];
  __shared__ __align__(16) u16   s_ch[TB * 164];
  __shared__ __align__(16) float s_tpt[36 * 32];
  __shared__ __align__(16) u16   s_g[TB * 136];
  __shared__ __align__(16) float s_red[3264];

  const int t = threadIdx.x;
  const int ib0 = blockIdx.x * TB;
  const int w = t >> 6, l = t & 63;
  const int rl = l & 15, q = l >> 4;

  //---- sentinels ----
  {  // s_ch: h[16]=1.0, h[17]=0 for every (row, c, a)  (exactly 512 slots)
    const int row = t >> 4, cc = (t >> 3) & 1, aa = (t >> 1) & 3, sl = t & 1;
    s_ch[row * 164 + cc * 80 + aa * 20 + 16 + sl] = sl ? (u16)0 : (u16)0x3F80;
  }
  if (t < 128) {  // s_tpt p=8 row = 1.0
    const int aa = t >> 5, row = t & 31;
    s_tpt[(aa * 9 + 8) * 32 + row] = 1.0f;
  }

  //---- stage te -> s_red[32][33], nh -> s_u bf16 [32][520] ----
  if (t < 256) {
    const int row = t >> 3, k4 = t & 7;
    f4 v = *(const f4*)&te[(size_t)(ib0 + row) * 32 + k4 * 4];
    float* d = &s_red[row * 33 + k4 * 4];
    d[0] = v.x; d[1] = v.y; d[2] = v.z; d[3] = v.w;
  }
  for (int lp = t; lp < 4096; lp += NTHR) {
    const int row = lp >> 7, rem = lp & 127;
    const int c = rem >> 6, k0 = (rem & 63) * 4;
    f4 v = *(const f4*)&nh[((size_t)(ib0 + row) * 2 + c) * 256 + k0];
    *(uint2*)&s_u[row * 520 + c * 256 + k0] =
        make_uint2(cvtpk(v.x, v.y), cvtpk(v.z, v.w));
  }
  __syncthreads();

  //---- Phase B: tp = te @ Ut + bt -> s_tpt (transposed, f32) ----
  {
    const int i = t >> 4, o = t & 15;
    const int off = o * 2;
    const int aa = off >> 3, p0 = off & 7;
    float acc0 = bt[off], acc1 = bt[off + 1];
    #pragma unroll
    for (int k = 0; k < 32; ++k) {
      float tv = s_red[i * 33 + k];
      float2 u = *(const float2*)&Ut[k * 32 + off];
      acc0 = fmaf(tv, u.x, acc0);
      acc1 = fmaf(tv, u.y, acc1);
    }
    s_tpt[(aa * 9 + p0) * 32 + i]     = acc0;
    s_tpt[(aa * 9 + p0 + 1) * 32 + i] = acc1;
  }

  //---- Phase C: ch = nh @ U + bw -> s_ch. Wave (c, a): both m, 2 MFMA/frag ----
  {
    const int c = w >> 2, a = w & 3;
    const u16* u0 = &UcTf[((size_t)((c * 4 + a) * 8) * 64 + l) * 8];
    bf16x8 C0 = *(const bf16x8*)(u0 + 0 * 512);
    bf16x8 C1 = *(const bf16x8*)(u0 + 1 * 512);
    bf16x8 C2 = *(const bf16x8*)(u0 + 2 * 512);
    bf16x8 C3 = *(const bf16x8*)(u0 + 3 * 512);
    bf16x8 C4 = *(const bf16x8*)(u0 + 4 * 512);
    bf16x8 C5 = *(const bf16x8*)(u0 + 5 * 512);
    bf16x8 C6 = *(const bf16x8*)(u0 + 6 * 512);
    bf16x8 C7 = *(const bf16x8*)(u0 + 7 * 512);
    f32x4 ac0 = {0.f, 0.f, 0.f, 0.f}, ac1 = {0.f, 0.f, 0.f, 0.f};
    #define PCKT(KT, CB)                                                          \
    {                                                                             \
      bf16x8 A0_ = *(const bf16x8*)&s_u[rl * 520 + c * 256 + KT * 32 + 8 * q];    \
      bf16x8 A1_ = *(const bf16x8*)&s_u[(16 + rl) * 520 + c * 256 + KT * 32 + 8 * q]; \
      ac0 = MFMA_B(A0_, CB, ac0);                                                 \
      ac1 = MFMA_B(A1_, CB, ac1);                                                 \
    }
    PCKT(0, C0) PCKT(1, C1) PCKT(2, C2) PCKT(3, C3)
    PCKT(4, C4) PCKT(5, C5) PCKT(6, C6) PCKT(7, C7)
    #undef PCKT
    const float bias = bw[(c * 4 + a) * 16 + rl];
    #pragma unroll
    for (int reg = 0; reg < 4; ++reg) {
      s_ch[(4 * q + reg) * 164 + c * 80 + a * 20 + rl]      = f2b(ac0[reg] + bias);
      s_ch[(16 + 4 * q + reg) * 164 + c * 80 + a * 20 + rl] = f2b(ac1[reg] + bias);
    }
  }
  __syncthreads();   // s_ch, s_tpt ready; nh reads done (s_u reusable)

  //---- Core: 2 a-pair iterations; wave = (aL, kq 4-way k-split), both m ----
  const int aL = w >> 2;
  const int kq = w & 3;
  const int kt0 = (kq <= 2) ? kq * 3 : 8;   // kt groups {0-2},{3-5},{6-7},{8-9}
  const int ktn = (kq < 2) ? 3 : 2;

  for (int it = 0; it < 2; ++it) {
    const int aB = it * 2;
    const int a = aB + aL;

    // prefetch first kt's 9 B frags — latency hides under O-build
    bf16x8 Bv0, Bv1, Bv2, Bv3, Bv4, Bv5, Bv6, Bv7, Bv8;
    LOADB(kt0);

    //-- O-build for BOTH aggregators of the pair: 1152 units (row, aLb, qv) --
    for (int lp = t; lp < 1152; lp += NTHR) {
      const int row = lp & 31, rest = lp >> 5;      // rest 0..35
      const int aLb = (rest >= 18) ? 1 : 0;
      const int qv = rest - aLb * 18;               // 0..17 (17: h1 sentinel=0)
      const int ab = aB + aLb;
      const float h1f = b2f(s_ch[row * 164 + ab * 20 + qv]);
      const u16* h2p = &s_ch[row * 164 + 80 + ab * 20];
      uint2 ha = *(const uint2*)&h2p[0];
      uint2 hb = *(const uint2*)&h2p[4];
      uint2 hc = *(const uint2*)&h2p[8];
      uint2 hd = *(const uint2*)&h2p[12];
      unsigned he = *(const unsigned*)&h2p[16];
      unsigned* op = (unsigned*)&s_u[aLb * 10496 + row * 328 + qv * 18];
      op[0] = cvtpk(h1f * blo(ha.x), h1f * bhi(ha.x));
      op[1] = cvtpk(h1f * blo(ha.y), h1f * bhi(ha.y));
      op[2] = cvtpk(h1f * blo(hb.x), h1f * bhi(hb.x));
      op[3] = cvtpk(h1f * blo(hb.y), h1f * bhi(hb.y));
      op[4] = cvtpk(h1f * blo(hc.x), h1f * bhi(hc.x));
      op[5] = cvtpk(h1f * blo(hc.y), h1f * bhi(hc.y));
      op[6] = cvtpk(h1f * blo(hd.x), h1f * bhi(hd.x));
      op[7] = cvtpk(h1f * blo(hd.y), h1f * bhi(hd.y));
      op[8] = cvtpk(h1f * blo(he),   h1f * bhi(he));
    }
    __syncthreads();

    //-- MFMA burst: per kt {9 B loads then 18 MFMAs (both m)} --
    f32x4 acc[9][2];
    #pragma unroll
    for (int p = 0; p < 9; ++p) {
      acc[p][0] = (f32x4){0.f, 0.f, 0.f, 0.f};
      acc[p][1] = (f32x4){0.f, 0.f, 0.f, 0.f};
    }
    __builtin_amdgcn_s_setprio(1);
    MFMA18(kt0);
    for (int kk = 1; kk < ktn; ++kk) {
      LOADB(kt0 + kk);
      MFMA18(kt0 + kk);
    }
    __builtin_amdgcn_s_setprio(0);

    //-- h0-weighted epilogue (f32-exact; k-split commutes) --
    float gp[2][4] = {{0.f, 0.f, 0.f, 0.f}, {0.f, 0.f, 0.f, 0.f}};
    #pragma unroll
    for (int p = 0; p < 9; ++p) {
      #pragma unroll
      for (int mm = 0; mm < 2; ++mm) {
        f4 tv = *(const f4*)&s_tpt[(a * 9 + p) * 32 + mm * 16 + 4 * q];
        gp[mm][0] = fmaf(tv.x, acc[p][mm][0], gp[mm][0]);
        gp[mm][1] = fmaf(tv.y, acc[p][mm][1], gp[mm][1]);
        gp[mm][2] = fmaf(tv.z, acc[p][mm][2], gp[mm][2]);
        gp[mm][3] = fmaf(tv.w, acc[p][mm][3], gp[mm][3]);
      }
    }
    if (kq) {
      #pragma unroll
      for (int mm = 0; mm < 2; ++mm)
        #pragma unroll
        for (int reg = 0; reg < 4; ++reg)
          s_red[((kq - 1) * 2 + aL) * 544 + mm * 272 + (4 * q + reg) * 17 + rl] =
              gp[mm][reg];
    }
    __syncthreads();

    if (kq == 0) {
      #pragma unroll
      for (int mm = 0; mm < 2; ++mm)
        #pragma unroll
        for (int reg = 0; reg < 4; ++reg) {
          const int idx = aL * 544 + mm * 272 + (4 * q + reg) * 17 + rl;
          float g = gp[mm][reg] + s_red[idx] + s_red[1088 + idx] + s_red[2176 + idx];
          const int row = mm * 16 + 4 * q + reg;
          s_g[row * 136 + a * 32 + rl]      = f2b(g);
          s_g[row * 136 + a * 32 + 16 + rl] = 0;
        }
    }
  }
  __syncthreads();   // s_g ready for all waves

  //---- Phase E: out = g @ U_output + b_output. Wave e: ht {2e, 2e+1}, both m ----
  {
    const int e = w;
    #pragma unroll
    for (int a = 0; a < 4; ++a) {
      const u16* ub = &UOTf[((size_t)(a * 16 + e * 2) * 64 + l) * 8];
      bf16x8 E0 = *(const bf16x8*)(ub);
      bf16x8 E1 = *(const bf16x8*)(ub + 512);
      bf16x8 A0 = *(const bf16x8*)&s_g[rl * 136 + a * 32 + 8 * q];
      bf16x8 A1 = *(const bf16x8*)&s_g[(16 + rl) * 136 + a * 32 + 8 * q];
      const float b0 = bO[a * 256 + (e * 2 + 0) * 16 + rl];
      const float b1 = bO[a * 256 + (e * 2 + 1) * 16 + rl];
      f32x4 e00 = {b0, b0, b0, b0}, e01 = e00;
      f32x4 e10 = {b1, b1, b1, b1}, e11 = e10;
      e00 = MFMA_B(A0, E0, e00);
      e01 = MFMA_B(A1, E0, e01);
      e10 = MFMA_B(A0, E1, e10);
      e11 = MFMA_B(A1, E1, e11);
      #pragma unroll
      for (int reg = 0; reg < 4; ++reg) {
        const size_t r0 = (size_t)(ib0 + 4 * q + reg) * 1024 + a * 256;
        const size_t r1 = (size_t)(ib0 + 16 + 4 * q + reg) * 1024 + a * 256;
        out[r0 + (e * 2 + 0) * 16 + rl] = e00[reg];
        out[r1 + (e * 2 + 0) * 16 + rl] = e01[reg];
        out[r0 + (e * 2 + 1) * 16 + rl] = e10[reg];
        out[r1 + (e * 2 + 1) * 16 + rl] = e11[reg];
      }
    }
  }
}

extern "C" void kernel_launch(void* const* d_in, const int* in_sizes, int n_in,
                              void* d_out, int out_size, void* d_ws, size_t ws_size,
                              hipStream_t stream) {
  const float* nh = (const float*)d_in[0];
  const float* te = (const float*)d_in[1];
  const float* U  = (const float*)d_in[2];
  const float* bw = (const float*)d_in[3];
  const float* Ut = (const float*)d_in[4];
  const float* bt = (const float*)d_in[5];
  const float* T  = (const float*)d_in[6];
  const float* UO = (const float*)d_in[7];
  const float* bO = (const float*)d_in[8];
  float* out = (float*)d_out;

  unsigned* ws32 = (unsigned*)d_ws;
  hipLaunchKernelGGL(hosvd_prep, dim3(488), dim3(256), 0, stream, U, T, UO, ws32);

  const u16* BTf  = (const u16*)d_ws;         // 184320 u16
  const u16* UcTf = BTf + 184320;             // 32768 u16
  const u16* UOTf = UcTf + 32768;             // 32768 u16

  const int bs = in_sizes[0] / 512;           // (BS,2,256)
  hipLaunchKernelGGL(hosvd_main, dim3(bs / TB), dim3(NTHR), 0, stream,
                     nh, te, bw, Ut, bt, bO, BTf, UcTf, UOTf, out);
}